// Round 8
// baseline (360.069 us; speedup 1.0000x reference)
//
#include <hip/hip_runtime.h>

#define DD 1280
#define SS 2048
#define HH 20

typedef __bf16 bf16x8 __attribute__((ext_vector_type(8)));
typedef float f32x4 __attribute__((ext_vector_type(4)));

typedef __attribute__((address_space(3))) unsigned int lds_uint;
typedef __attribute__((address_space(1))) unsigned int glb_uint;
#define GLL16(g, l) __builtin_amdgcn_global_load_lds((const glb_uint*)(g), (lds_uint*)(l), 16, 0, 0)

__device__ __forceinline__ unsigned short f2bf(float f) {
  union { float f; unsigned u; } v; v.f = f;
  unsigned r = v.u + 0x7fffu + ((v.u >> 16) & 1u);
  return (unsigned short)(r >> 16);
}
__device__ __forceinline__ unsigned f2u(float f) {
  union { float f; unsigned u; } v; v.f = f; return v.u;
}

// ---- prep: cast X to bf16; transpose-cast W -> WT[n][k]; rotary cos/sin table ----
__global__ __launch_bounds__(256) void prep_kernel(
    const float* __restrict__ X, const float* __restrict__ Wq,
    const float* __restrict__ Wk, const float* __restrict__ Wv,
    unsigned short* __restrict__ Xb, unsigned short* __restrict__ WT,
    float2* __restrict__ cs) {
  __shared__ unsigned short tile[32][33];
  int bid = blockIdx.x, tid = threadIdx.x;
  if (bid < 2560) {
    size_t base = (size_t)bid * 2048 + (size_t)tid * 8;
    const float4* xin = (const float4*)(X + base);
    float4 a = xin[0], c = xin[1];
    ushort4 o0 = make_ushort4(f2bf(a.x), f2bf(a.y), f2bf(a.z), f2bf(a.w));
    ushort4 o1 = make_ushort4(f2bf(c.x), f2bf(c.y), f2bf(c.z), f2bf(c.w));
    *(ushort4*)(Xb + base) = o0;
    *(ushort4*)(Xb + base + 4) = o1;
  } else if (bid < 7360) {
    int wb = bid - 2560;          // 3 * 1600 tiles of 32x32
    int mat = wb / 1600;
    int t = wb % 1600;
    int tn = t % 40, tk = t / 40;
    const float* W = (mat == 0) ? Wq : ((mat == 1) ? Wk : Wv);
    int k0 = tk * 32, n0 = tn * 32;
    int tc = tid & 31, tr = tid >> 5;
#pragma unroll
    for (int i = 0; i < 4; i++) {
      int kl = tr + i * 8;
      tile[kl][tc] = f2bf(W[(size_t)(k0 + kl) * DD + n0 + tc]);
    }
    __syncthreads();
    unsigned short* out = WT + (size_t)mat * DD * DD;
#pragma unroll
    for (int i = 0; i < 4; i++) {
      int nl = tr + i * 8;
      out[(size_t)(n0 + nl) * DD + k0 + tc] = tile[tc][nl];
    }
  } else {
    // rotary table: cs[sp][j] = (cos, sin)(sp * 10000^(-j/32)), 2048 x 32
    int idx = (bid - 7360) * 256 + tid;     // 256 blocks -> 65536 entries
    int sp = idx >> 5, j = idx & 31;
    float invf = exp2f(-(float)j * 0.41524101186092034f);
    float ang = (float)sp * invf;
    cs[idx] = make_float2(cosf(ang), sinf(ang));
  }
}

// ---- QKV GEMM (m97 structure) + fused bias + rotary (table) epilogue ----
// Q additionally scaled by HD^-0.5 * log2(e) so attention can use exp2 directly.
__global__ __launch_bounds__(256) void qkv_gemm_kernel(
    const unsigned short* __restrict__ Xb, const unsigned short* __restrict__ WT,
    const float* __restrict__ bq, const float* __restrict__ bk, const float* __restrict__ bv,
    const float2* __restrict__ cs,
    unsigned short* __restrict__ Qr, unsigned short* __restrict__ Kr,
    unsigned short* __restrict__ VT) {
  __shared__ __align__(16) unsigned short As[128 * 32];
  __shared__ __align__(16) unsigned short Bs[128 * 32];
  int bx = blockIdx.x;            // 3 * 32 * 10
  int mat = bx / 320;
  int r0 = bx % 320;
  int tm = r0 / 10, tn = r0 % 10;
  int m0 = tm * 128, n0 = tn * 128;
  int tid = threadIdx.x;
  int lane = tid & 63, wave = tid >> 6;
  int c15 = lane & 15, quad = lane >> 4;
  int wm = wave >> 1, wn = wave & 1;
  const unsigned short* Wm = WT + (size_t)mat * DD * DD;

  int rowA = tid >> 2;
  int c8 = (tid & 3) * 8;
  const unsigned short* gA0 = Xb + (size_t)(m0 + rowA) * DD + c8;
  const unsigned short* gA1 = gA0 + (size_t)64 * DD;
  const unsigned short* gB0 = Wm + (size_t)(n0 + rowA) * DD + c8;
  const unsigned short* gB1 = gB0 + (size_t)64 * DD;
  unsigned short* ldsA0 = As + wave * 512;          // rows 0..63
  unsigned short* ldsA1 = As + 2048 + wave * 512;   // rows 64..127
  unsigned short* ldsB0 = Bs + wave * 512;
  unsigned short* ldsB1 = Bs + 2048 + wave * 512;

  f32x4 acc[4][4] = {};

  for (int kk = 0; kk < DD; kk += 32) {
    __syncthreads();
    GLL16(gA0 + kk, ldsA0);
    GLL16(gA1 + kk, ldsA1);
    GLL16(gB0 + kk, ldsB0);
    GLL16(gB1 + kk, ldsB1);
    __syncthreads();
    bf16x8 af[4];
#pragma unroll
    for (int mi = 0; mi < 4; mi++)
      af[mi] = *(const bf16x8*)(As + (wm * 64 + mi * 16 + c15) * 32 + quad * 8);
#pragma unroll
    for (int ni = 0; ni < 4; ni++) {
      bf16x8 bfr = *(const bf16x8*)(Bs + (wn * 64 + ni * 16 + c15) * 32 + quad * 8);
#pragma unroll
      for (int mi = 0; mi < 4; mi++)
        acc[mi][ni] = __builtin_amdgcn_mfma_f32_16x16x32_bf16(af[mi], bfr, acc[mi][ni], 0, 0, 0);
    }
  }

  int growb = m0 + wm * 64;
  int gcolb = n0 + wn * 64;
  if (mat == 2) {
    // V: write transposed VT[(b*H+h)*64+d][s]
#pragma unroll
    for (int mi = 0; mi < 4; mi++) {
      int row0 = growb + mi * 16 + quad * 4;
      int bb_ = row0 >> 11, sp = row0 & 2047;
#pragma unroll
      for (int ni = 0; ni < 4; ni++) {
        int gcol = gcolb + ni * 16 + c15;
        float bias = bv[gcol];
        int hh = gcol >> 6, dd = gcol & 63;
        f32x4 v = acc[mi][ni];
        ushort4 o = make_ushort4(f2bf(v[0] + bias), f2bf(v[1] + bias),
                                 f2bf(v[2] + bias), f2bf(v[3] + bias));
        *(ushort4*)(VT + ((size_t)((bb_ * HH + hh) * 64 + dd)) * SS + sp) = o;
      }
    }
  } else {
    // Q / K: bias + rotary via cs table; each wave's 64 cols = exactly one head,
    // rotary pair (d, d+32) = acc frags (ni, ni+2), same lane.
    unsigned short* Out = (mat == 0) ? Qr : Kr;
    const float* bias = (mat == 0) ? bq : bk;
    float qs = (mat == 0) ? 0.18033688011112042f : 1.0f;  // 0.125*log2(e) for Q
#pragma unroll
    for (int mi = 0; mi < 4; mi++) {
      int row0 = growb + mi * 16 + quad * 4;
#pragma unroll
      for (int ni = 0; ni < 2; ni++) {
        int gcol_lo = gcolb + ni * 16 + c15;      // d in [0,32) within head
        int gcol_hi = gcol_lo + 32;
        float blo = bias[gcol_lo], bhi = bias[gcol_hi];
        int d = ni * 16 + c15;
        f32x4 lo = acc[mi][ni], hi = acc[mi][ni + 2];
#pragma unroll
        for (int r = 0; r < 4; r++) {
          int grow = row0 + r;
          float2 cv = cs[(size_t)(grow & 2047) * 32 + d];
          float xl = (lo[r] + blo) * qs, xh = (hi[r] + bhi) * qs;
          Out[(size_t)grow * DD + gcol_lo] = f2bf(xl * cv.x - xh * cv.y);
          Out[(size_t)grow * DD + gcol_hi] = f2bf(xh * cv.x + xl * cv.y);
        }
      }
    }
  }
}

// ---- flash attention v5: key-split waves, barrier-free K-loop,
//      LDS overlay (Obuf reuses Pall after the loop -> 33 KB -> 4 blocks/CU),
//      l accumulated via MFMA P*ones (bit-consistent with PV numerator) ----
__global__ __launch_bounds__(256)
__attribute__((amdgpu_waves_per_eu(3, 8)))
void attn_kernel(
    const unsigned short* __restrict__ Qr, const unsigned short* __restrict__ Kr,
    const unsigned short* __restrict__ VT, float* __restrict__ out) {
  __shared__ __align__(16) unsigned short Pall[4 * 64 * 64];  // 32 KB: per-wave P strips
  __shared__ float Lbuf[64];
  int bx = blockIdx.x;             // bx = qt*40 + bh; 40%8==0 -> head pinned to one XCD
  int bh = bx % 40, qt = bx / 40;
  int b = bh / HH, h = bh % HH;
  int tid = threadIdx.x;
  int lane = tid & 63, w = tid >> 6;
  int c15 = lane & 15, quad = lane >> 4;
  int q0 = qt * 64;

  // Q frags direct from global (A-layout: lane m=c15, k=quad*8), kept in regs
  const unsigned short* Qbase = Qr + (size_t)(b * SS + q0) * DD + h * 64;
  bf16x8 qf[4][2];
#pragma unroll
  for (int mi = 0; mi < 4; mi++)
#pragma unroll
    for (int kc = 0; kc < 2; kc++)
      qf[mi][kc] = *(const bf16x8*)(Qbase + (size_t)(mi * 16 + c15) * DD + kc * 32 + quad * 8);

  const unsigned short* Kbase = Kr + (size_t)(b * SS + w * 32) * DD + h * 64;
  const unsigned short* Vbase = VT + (size_t)(bh * 64) * SS + w * 32;
  unsigned short* Pw = Pall + w * 4096;   // 64 rows x 64 shorts

  bf16x8 ones;
#pragma unroll
  for (int i = 0; i < 8; i++) ones[i] = (__bf16)1.0f;

  f32x4 of[4][4] = {};       // [mi][nio]
  f32x4 ol[4] = {};          // l via P*ones: row q=mi*16+quad*4+r, replicated over c15

  for (int t = 0; t < 16; t++) {
    const unsigned short* Kt = Kbase + (size_t)(t * 128) * DD;
    const unsigned short* Vt = Vbase + t * 128;
    // K B-frags (n=key, k=d) and V B-frags (n=d, k=key) direct to regs
    bf16x8 kf[2][2], vf[4];
#pragma unroll
    for (int ni = 0; ni < 2; ni++)
#pragma unroll
      for (int kc = 0; kc < 2; kc++)
        kf[ni][kc] = *(const bf16x8*)(Kt + (size_t)(ni * 16 + c15) * DD + kc * 32 + quad * 8);
#pragma unroll
    for (int nio = 0; nio < 4; nio++)
      vf[nio] = *(const bf16x8*)(Vt + (size_t)(nio * 16 + c15) * SS + quad * 8);

    // S = Q K^T  (64q x 32k per wave)
    f32x4 sc[4][2] = {};
#pragma unroll
    for (int ni = 0; ni < 2; ni++)
#pragma unroll
      for (int kc = 0; kc < 2; kc++)
#pragma unroll
        for (int mi = 0; mi < 4; mi++)
          sc[mi][ni] = __builtin_amdgcn_mfma_f32_16x16x32_bf16(qf[mi][kc], kf[ni][kc], sc[mi][ni], 0, 0, 0);

    // P = exp2(S) (Q pre-scaled by log2e/8); truncate to bf16 into swizzled strip
#pragma unroll
    for (int mi = 0; mi < 4; mi++)
#pragma unroll
      for (int ni = 0; ni < 2; ni++) {
        int kc8 = ni * 2 + (c15 >> 3);
#pragma unroll
        for (int r = 0; r < 4; r++) {
          unsigned u = f2u(__builtin_amdgcn_exp2f(sc[mi][ni][r]));
          int q = mi * 16 + quad * 4 + r;
          int pos = (kc8 + 2 * quad + r) & 7;
          Pw[q * 64 + pos * 8 + (c15 & 7)] = (unsigned short)(u >> 16);
        }
      }

    // O += P V ; l += P * 1   (A-frag from swizzled strip)
#pragma unroll
    for (int mi = 0; mi < 4; mi++) {
      int pos = (quad + 2 * ((c15 >> 2) & 3) + (c15 & 3)) & 7;
      bf16x8 pf = *(const bf16x8*)(Pw + (mi * 16 + c15) * 64 + pos * 8);
#pragma unroll
      for (int nio = 0; nio < 4; nio++)
        of[mi][nio] = __builtin_amdgcn_mfma_f32_16x16x32_bf16(pf, vf[nio], of[mi][nio], 0, 0, 0);
      ol[mi] = __builtin_amdgcn_mfma_f32_16x16x32_bf16(pf, ones, ol[mi], 0, 0, 0);
    }
  }

  // all waves done with their P strips -> safe to overlay Obuf on Pall
  __syncthreads();
  float* Obuf = (float*)Pall;      // 64 x 65 floats = 16.6 KB of the 32 KB strip area

  // cross-wave reduction of O and l (serialized passes)
  for (int pass = 0; pass < 4; pass++) {
    if (w == pass) {
#pragma unroll
      for (int mi = 0; mi < 4; mi++)
#pragma unroll
        for (int nio = 0; nio < 4; nio++)
#pragma unroll
          for (int r = 0; r < 4; r++) {
            int q = mi * 16 + quad * 4 + r;
            int d = nio * 16 + c15;
            if (pass == 0) Obuf[q * 65 + d] = of[mi][nio][r];
            else           Obuf[q * 65 + d] += of[mi][nio][r];
          }
      if (c15 == 0) {
#pragma unroll
        for (int mi = 0; mi < 4; mi++)
#pragma unroll
          for (int r = 0; r < 4; r++) {
            int q = mi * 16 + quad * 4 + r;
            if (pass == 0) Lbuf[q] = ol[mi][r];
            else           Lbuf[q] += ol[mi][r];
          }
      }
    }
    __syncthreads();
  }

  // epilogue: each wave writes 16 q-rows; lane covers 16 consecutive d
  {
    int row = w * 16 + (lane >> 2);
    int col0 = (lane & 3) * 16;
    float invl = 1.0f / Lbuf[row];
    float* op = out + (size_t)(b * SS + q0 + row) * DD + h * 64 + col0;
    const float* ob = Obuf + row * 65 + col0;
#pragma unroll
    for (int j = 0; j < 4; j++) {
      float4 v = make_float4(ob[j * 4 + 0] * invl, ob[j * 4 + 1] * invl,
                             ob[j * 4 + 2] * invl, ob[j * 4 + 3] * invl);
      *(float4*)(op + j * 4) = v;
    }
  }
}

extern "C" void kernel_launch(void* const* d_in, const int* in_sizes, int n_in,
                              void* d_out, int out_size, void* d_ws, size_t ws_size,
                              hipStream_t stream) {
  (void)in_sizes; (void)n_in; (void)out_size; (void)ws_size;
  const float* X  = (const float*)d_in[0];
  const float* Wq = (const float*)d_in[1];
  const float* bq = (const float*)d_in[2];
  const float* Wk = (const float*)d_in[3];
  const float* bk = (const float*)d_in[4];
  const float* Wv = (const float*)d_in[5];
  const float* bv = (const float*)d_in[6];
  char* ws = (char*)d_ws;
  unsigned short* Xb  = (unsigned short*)(ws);                 // 4096x1280 bf16
  unsigned short* WT  = (unsigned short*)(ws + 10485760);      // 3x1280x1280 bf16 (transposed)
  unsigned short* Qr  = (unsigned short*)(ws + 20316160);      // 4096x1280 bf16 (rotary'd, scaled)
  unsigned short* Kr  = (unsigned short*)(ws + 30801920);      // 4096x1280 bf16 (rotary'd)
  unsigned short* VTt = (unsigned short*)(ws + 41287680);      // [40][64][2048] bf16
  float2* cstab       = (float2*)(ws + 51773440);              // 2048x32 float2
  hipLaunchKernelGGL(prep_kernel, dim3(7616), dim3(256), 0, stream, X, Wq, Wk, Wv, Xb, WT, cstab);
  hipLaunchKernelGGL(qkv_gemm_kernel, dim3(960), dim3(256), 0, stream, Xb, WT, bq, bk, bv, cstab, Qr, Kr, VTt);
  hipLaunchKernelGGL(attn_kernel, dim3(1280), dim3(256), 0, stream, Qr, Kr, VTt, (float*)d_out);
}

// Round 9
// 265.246 us; speedup vs baseline: 1.3575x; 1.3575x over previous
//
#include <hip/hip_runtime.h>

#define DD 1280
#define SS 2048
#define HH 20

typedef __bf16 bf16x8 __attribute__((ext_vector_type(8)));
typedef float f32x4 __attribute__((ext_vector_type(4)));

typedef __attribute__((address_space(3))) unsigned int lds_uint;
typedef __attribute__((address_space(1))) unsigned int glb_uint;
#define GLL16(g, l) __builtin_amdgcn_global_load_lds((const glb_uint*)(g), (lds_uint*)(l), 16, 0, 0)

__device__ __forceinline__ unsigned short f2bf(float f) {
  union { float f; unsigned u; } v; v.f = f;
  unsigned r = v.u + 0x7fffu + ((v.u >> 16) & 1u);
  return (unsigned short)(r >> 16);
}
__device__ __forceinline__ unsigned f2u(float f) {
  union { float f; unsigned u; } v; v.f = f; return v.u;
}

// ---- prep: cast X to bf16; transpose-cast W -> WT[n][k]; rotary cos/sin table ----
__global__ __launch_bounds__(256) void prep_kernel(
    const float* __restrict__ X, const float* __restrict__ Wq,
    const float* __restrict__ Wk, const float* __restrict__ Wv,
    unsigned short* __restrict__ Xb, unsigned short* __restrict__ WT,
    float2* __restrict__ cs) {
  __shared__ unsigned short tile[32][33];
  int bid = blockIdx.x, tid = threadIdx.x;
  if (bid < 2560) {
    size_t base = (size_t)bid * 2048 + (size_t)tid * 8;
    const float4* xin = (const float4*)(X + base);
    float4 a = xin[0], c = xin[1];
    ushort4 o0 = make_ushort4(f2bf(a.x), f2bf(a.y), f2bf(a.z), f2bf(a.w));
    ushort4 o1 = make_ushort4(f2bf(c.x), f2bf(c.y), f2bf(c.z), f2bf(c.w));
    *(ushort4*)(Xb + base) = o0;
    *(ushort4*)(Xb + base + 4) = o1;
  } else if (bid < 7360) {
    int wb = bid - 2560;          // 3 * 1600 tiles of 32x32
    int mat = wb / 1600;
    int t = wb % 1600;
    int tn = t % 40, tk = t / 40;
    const float* W = (mat == 0) ? Wq : ((mat == 1) ? Wk : Wv);
    int k0 = tk * 32, n0 = tn * 32;
    int tc = tid & 31, tr = tid >> 5;
#pragma unroll
    for (int i = 0; i < 4; i++) {
      int kl = tr + i * 8;
      tile[kl][tc] = f2bf(W[(size_t)(k0 + kl) * DD + n0 + tc]);
    }
    __syncthreads();
    unsigned short* out = WT + (size_t)mat * DD * DD;
#pragma unroll
    for (int i = 0; i < 4; i++) {
      int nl = tr + i * 8;
      out[(size_t)(n0 + nl) * DD + k0 + tc] = tile[tc][nl];
    }
  } else {
    // rotary table: cs[sp][j] = (cos, sin)(sp * 10000^(-j/32)), 2048 x 32
    int idx = (bid - 7360) * 256 + tid;     // 256 blocks -> 65536 entries
    int sp = idx >> 5, j = idx & 31;
    float invf = exp2f(-(float)j * 0.41524101186092034f);
    float ang = (float)sp * invf;
    cs[idx] = make_float2(cosf(ang), sinf(ang));
  }
}

// ---- QKV GEMM (m97 structure) + fused bias + rotary (table) epilogue ----
// Q additionally scaled by HD^-0.5 * log2(e) so attention can use exp2 directly.
__global__ __launch_bounds__(256) void qkv_gemm_kernel(
    const unsigned short* __restrict__ Xb, const unsigned short* __restrict__ WT,
    const float* __restrict__ bq, const float* __restrict__ bk, const float* __restrict__ bv,
    const float2* __restrict__ cs,
    unsigned short* __restrict__ Qr, unsigned short* __restrict__ Kr,
    unsigned short* __restrict__ VT) {
  __shared__ __align__(16) unsigned short As[128 * 32];
  __shared__ __align__(16) unsigned short Bs[128 * 32];
  int bx = blockIdx.x;            // 3 * 32 * 10
  int mat = bx / 320;
  int r0 = bx % 320;
  int tm = r0 / 10, tn = r0 % 10;
  int m0 = tm * 128, n0 = tn * 128;
  int tid = threadIdx.x;
  int lane = tid & 63, wave = tid >> 6;
  int c15 = lane & 15, quad = lane >> 4;
  int wm = wave >> 1, wn = wave & 1;
  const unsigned short* Wm = WT + (size_t)mat * DD * DD;

  int rowA = tid >> 2;
  int c8 = (tid & 3) * 8;
  const unsigned short* gA0 = Xb + (size_t)(m0 + rowA) * DD + c8;
  const unsigned short* gA1 = gA0 + (size_t)64 * DD;
  const unsigned short* gB0 = Wm + (size_t)(n0 + rowA) * DD + c8;
  const unsigned short* gB1 = gB0 + (size_t)64 * DD;
  unsigned short* ldsA0 = As + wave * 512;          // rows 0..63
  unsigned short* ldsA1 = As + 2048 + wave * 512;   // rows 64..127
  unsigned short* ldsB0 = Bs + wave * 512;
  unsigned short* ldsB1 = Bs + 2048 + wave * 512;

  f32x4 acc[4][4] = {};

  for (int kk = 0; kk < DD; kk += 32) {
    __syncthreads();
    GLL16(gA0 + kk, ldsA0);
    GLL16(gA1 + kk, ldsA1);
    GLL16(gB0 + kk, ldsB0);
    GLL16(gB1 + kk, ldsB1);
    __syncthreads();
    bf16x8 af[4];
#pragma unroll
    for (int mi = 0; mi < 4; mi++)
      af[mi] = *(const bf16x8*)(As + (wm * 64 + mi * 16 + c15) * 32 + quad * 8);
#pragma unroll
    for (int ni = 0; ni < 4; ni++) {
      bf16x8 bfr = *(const bf16x8*)(Bs + (wn * 64 + ni * 16 + c15) * 32 + quad * 8);
#pragma unroll
      for (int mi = 0; mi < 4; mi++)
        acc[mi][ni] = __builtin_amdgcn_mfma_f32_16x16x32_bf16(af[mi], bfr, acc[mi][ni], 0, 0, 0);
    }
  }

  int growb = m0 + wm * 64;
  int gcolb = n0 + wn * 64;
  if (mat == 2) {
    // V: write transposed VT[(b*H+h)*64+d][s]
#pragma unroll
    for (int mi = 0; mi < 4; mi++) {
      int row0 = growb + mi * 16 + quad * 4;
      int bb_ = row0 >> 11, sp = row0 & 2047;
#pragma unroll
      for (int ni = 0; ni < 4; ni++) {
        int gcol = gcolb + ni * 16 + c15;
        float bias = bv[gcol];
        int hh = gcol >> 6, dd = gcol & 63;
        f32x4 v = acc[mi][ni];
        ushort4 o = make_ushort4(f2bf(v[0] + bias), f2bf(v[1] + bias),
                                 f2bf(v[2] + bias), f2bf(v[3] + bias));
        *(ushort4*)(VT + ((size_t)((bb_ * HH + hh) * 64 + dd)) * SS + sp) = o;
      }
    }
  } else {
    // Q / K: bias + rotary via cs table; each wave's 64 cols = exactly one head,
    // rotary pair (d, d+32) = acc frags (ni, ni+2), same lane.
    unsigned short* Out = (mat == 0) ? Qr : Kr;
    const float* bias = (mat == 0) ? bq : bk;
    float qs = (mat == 0) ? 0.18033688011112042f : 1.0f;  // 0.125*log2(e) for Q
#pragma unroll
    for (int mi = 0; mi < 4; mi++) {
      int row0 = growb + mi * 16 + quad * 4;
#pragma unroll
      for (int ni = 0; ni < 2; ni++) {
        int gcol_lo = gcolb + ni * 16 + c15;      // d in [0,32) within head
        int gcol_hi = gcol_lo + 32;
        float blo = bias[gcol_lo], bhi = bias[gcol_hi];
        int d = ni * 16 + c15;
        f32x4 lo = acc[mi][ni], hi = acc[mi][ni + 2];
#pragma unroll
        for (int r = 0; r < 4; r++) {
          int grow = row0 + r;
          float2 cv = cs[(size_t)(grow & 2047) * 32 + d];
          float xl = (lo[r] + blo) * qs, xh = (hi[r] + bhi) * qs;
          Out[(size_t)grow * DD + gcol_lo] = f2bf(xl * cv.x - xh * cv.y);
          Out[(size_t)grow * DD + gcol_hi] = f2bf(xh * cv.x + xl * cv.y);
        }
      }
    }
  }
}

// ---- flash attention v5b: key-split waves, barrier-free K-loop, Obuf/Pall
//      LDS overlay (33 KB -> 4 blocks/CU), l via MFMA P*ones.
//      waves_per_eu(2,4): min=2 keeps the 256-VGPR budget that ran round 7
//      spill-free (round-8 min=3 cut the budget to ~170 < the ~200 this kernel
//      needs -> 32 dwords/thread scratch, 42 MB writeback, 2x regression);
//      max=4 lets HW reach 4 waves/EU now that LDS and VGPR both permit. ----
__global__ __launch_bounds__(256)
__attribute__((amdgpu_waves_per_eu(2, 4)))
void attn_kernel(
    const unsigned short* __restrict__ Qr, const unsigned short* __restrict__ Kr,
    const unsigned short* __restrict__ VT, float* __restrict__ out) {
  __shared__ __align__(16) unsigned short Pall[4 * 64 * 64];  // 32 KB: per-wave P strips
  __shared__ float Lbuf[64];
  int bx = blockIdx.x;             // bx = qt*40 + bh; head pinned to one XCD
  int bh = bx % 40, qt = bx / 40;
  int b = bh / HH, h = bh % HH;
  int tid = threadIdx.x;
  int lane = tid & 63, w = tid >> 6;
  int c15 = lane & 15, quad = lane >> 4;
  int q0 = qt * 64;

  // Q frags direct from global (A-layout: lane m=c15, k=quad*8), kept in regs
  const unsigned short* Qbase = Qr + (size_t)(b * SS + q0) * DD + h * 64;
  bf16x8 qf[4][2];
#pragma unroll
  for (int mi = 0; mi < 4; mi++)
#pragma unroll
    for (int kc = 0; kc < 2; kc++)
      qf[mi][kc] = *(const bf16x8*)(Qbase + (size_t)(mi * 16 + c15) * DD + kc * 32 + quad * 8);

  const unsigned short* Kbase = Kr + (size_t)(b * SS + w * 32) * DD + h * 64;
  const unsigned short* Vbase = VT + (size_t)(bh * 64) * SS + w * 32;
  unsigned short* Pw = Pall + w * 4096;   // 64 rows x 64 shorts

  bf16x8 ones;
#pragma unroll
  for (int i = 0; i < 8; i++) ones[i] = (__bf16)1.0f;

  f32x4 of[4][4] = {};       // [mi][nio]
  f32x4 ol[4] = {};          // l via P*ones: row q=mi*16+quad*4+r, replicated over c15

  for (int t = 0; t < 16; t++) {
    const unsigned short* Kt = Kbase + (size_t)(t * 128) * DD;
    const unsigned short* Vt = Vbase + t * 128;
    // K B-frags (n=key, k=d) and V B-frags (n=d, k=key) direct to regs
    bf16x8 kf[2][2], vf[4];
#pragma unroll
    for (int ni = 0; ni < 2; ni++)
#pragma unroll
      for (int kc = 0; kc < 2; kc++)
        kf[ni][kc] = *(const bf16x8*)(Kt + (size_t)(ni * 16 + c15) * DD + kc * 32 + quad * 8);
#pragma unroll
    for (int nio = 0; nio < 4; nio++)
      vf[nio] = *(const bf16x8*)(Vt + (size_t)(nio * 16 + c15) * SS + quad * 8);

    // S = Q K^T  (64q x 32k per wave)
    f32x4 sc[4][2] = {};
#pragma unroll
    for (int ni = 0; ni < 2; ni++)
#pragma unroll
      for (int kc = 0; kc < 2; kc++)
#pragma unroll
        for (int mi = 0; mi < 4; mi++)
          sc[mi][ni] = __builtin_amdgcn_mfma_f32_16x16x32_bf16(qf[mi][kc], kf[ni][kc], sc[mi][ni], 0, 0, 0);

    // P = exp2(S) (Q pre-scaled by log2e/8); truncate to bf16 into swizzled strip
#pragma unroll
    for (int mi = 0; mi < 4; mi++)
#pragma unroll
      for (int ni = 0; ni < 2; ni++) {
        int kc8 = ni * 2 + (c15 >> 3);
#pragma unroll
        for (int r = 0; r < 4; r++) {
          unsigned u = f2u(__builtin_amdgcn_exp2f(sc[mi][ni][r]));
          int q = mi * 16 + quad * 4 + r;
          int pos = (kc8 + 2 * quad + r) & 7;
          Pw[q * 64 + pos * 8 + (c15 & 7)] = (unsigned short)(u >> 16);
        }
      }

    // O += P V ; l += P * 1   (A-frag from swizzled strip)
#pragma unroll
    for (int mi = 0; mi < 4; mi++) {
      int pos = (quad + 2 * ((c15 >> 2) & 3) + (c15 & 3)) & 7;
      bf16x8 pf = *(const bf16x8*)(Pw + (mi * 16 + c15) * 64 + pos * 8);
#pragma unroll
      for (int nio = 0; nio < 4; nio++)
        of[mi][nio] = __builtin_amdgcn_mfma_f32_16x16x32_bf16(pf, vf[nio], of[mi][nio], 0, 0, 0);
      ol[mi] = __builtin_amdgcn_mfma_f32_16x16x32_bf16(pf, ones, ol[mi], 0, 0, 0);
    }
  }

  // all waves done with their P strips -> safe to overlay Obuf on Pall
  __syncthreads();
  float* Obuf = (float*)Pall;      // 64 x 65 floats = 16.6 KB of the 32 KB strip area

  // cross-wave reduction of O and l (serialized passes)
  for (int pass = 0; pass < 4; pass++) {
    if (w == pass) {
#pragma unroll
      for (int mi = 0; mi < 4; mi++)
#pragma unroll
        for (int nio = 0; nio < 4; nio++)
#pragma unroll
          for (int r = 0; r < 4; r++) {
            int q = mi * 16 + quad * 4 + r;
            int d = nio * 16 + c15;
            if (pass == 0) Obuf[q * 65 + d] = of[mi][nio][r];
            else           Obuf[q * 65 + d] += of[mi][nio][r];
          }
      if (c15 == 0) {
#pragma unroll
        for (int mi = 0; mi < 4; mi++)
#pragma unroll
          for (int r = 0; r < 4; r++) {
            int q = mi * 16 + quad * 4 + r;
            if (pass == 0) Lbuf[q] = ol[mi][r];
            else           Lbuf[q] += ol[mi][r];
          }
      }
    }
    __syncthreads();
  }

  // epilogue: each wave writes 16 q-rows; lane covers 16 consecutive d
  {
    int row = w * 16 + (lane >> 2);
    int col0 = (lane & 3) * 16;
    float invl = 1.0f / Lbuf[row];
    float* op = out + (size_t)(b * SS + q0 + row) * DD + h * 64 + col0;
    const float* ob = Obuf + row * 65 + col0;
#pragma unroll
    for (int j = 0; j < 4; j++) {
      float4 v = make_float4(ob[j * 4 + 0] * invl, ob[j * 4 + 1] * invl,
                             ob[j * 4 + 2] * invl, ob[j * 4 + 3] * invl);
      *(float4*)(op + j * 4) = v;
    }
  }
}

extern "C" void kernel_launch(void* const* d_in, const int* in_sizes, int n_in,
                              void* d_out, int out_size, void* d_ws, size_t ws_size,
                              hipStream_t stream) {
  (void)in_sizes; (void)n_in; (void)out_size; (void)ws_size;
  const float* X  = (const float*)d_in[0];
  const float* Wq = (const float*)d_in[1];
  const float* bq = (const float*)d_in[2];
  const float* Wk = (const float*)d_in[3];
  const float* bk = (const float*)d_in[4];
  const float* Wv = (const float*)d_in[5];
  const float* bv = (const float*)d_in[6];
  char* ws = (char*)d_ws;
  unsigned short* Xb  = (unsigned short*)(ws);                 // 4096x1280 bf16
  unsigned short* WT  = (unsigned short*)(ws + 10485760);      // 3x1280x1280 bf16 (transposed)
  unsigned short* Qr  = (unsigned short*)(ws + 20316160);      // 4096x1280 bf16 (rotary'd, scaled)
  unsigned short* Kr  = (unsigned short*)(ws + 30801920);      // 4096x1280 bf16 (rotary'd)
  unsigned short* VTt = (unsigned short*)(ws + 41287680);      // [40][64][2048] bf16
  float2* cstab       = (float2*)(ws + 51773440);              // 2048x32 float2
  hipLaunchKernelGGL(prep_kernel, dim3(7616), dim3(256), 0, stream, X, Wq, Wk, Wv, Xb, WT, cstab);
  hipLaunchKernelGGL(qkv_gemm_kernel, dim3(960), dim3(256), 0, stream, Xb, WT, bq, bk, bv, cstab, Qr, Kr, VTt);
  hipLaunchKernelGGL(attn_kernel, dim3(1280), dim3(256), 0, stream, Qr, Kr, VTt, (float*)d_out);
}

// Round 10
// 247.266 us; speedup vs baseline: 1.4562x; 1.0727x over previous
//
#include <hip/hip_runtime.h>

#define DD 1280
#define SS 2048
#define HH 20

typedef __bf16 bf16x8 __attribute__((ext_vector_type(8)));
typedef float f32x4 __attribute__((ext_vector_type(4)));

typedef __attribute__((address_space(3))) unsigned int lds_uint;
typedef __attribute__((address_space(1))) unsigned int glb_uint;
#define GLL16(g, l) __builtin_amdgcn_global_load_lds((const glb_uint*)(g), (lds_uint*)(l), 16, 0, 0)

__device__ __forceinline__ unsigned short f2bf(float f) {
  union { float f; unsigned u; } v; v.f = f;
  unsigned r = v.u + 0x7fffu + ((v.u >> 16) & 1u);
  return (unsigned short)(r >> 16);
}
__device__ __forceinline__ unsigned f2u(float f) {
  union { float f; unsigned u; } v; v.f = f; return v.u;
}

// ---- prep: cast X to bf16; transpose-cast W -> WT[n][k]; rotary cos/sin table ----
__global__ __launch_bounds__(256) void prep_kernel(
    const float* __restrict__ X, const float* __restrict__ Wq,
    const float* __restrict__ Wk, const float* __restrict__ Wv,
    unsigned short* __restrict__ Xb, unsigned short* __restrict__ WT,
    float2* __restrict__ cs) {
  __shared__ unsigned short tile[32][33];
  int bid = blockIdx.x, tid = threadIdx.x;
  if (bid < 2560) {
    size_t base = (size_t)bid * 2048 + (size_t)tid * 8;
    const float4* xin = (const float4*)(X + base);
    float4 a = xin[0], c = xin[1];
    ushort4 o0 = make_ushort4(f2bf(a.x), f2bf(a.y), f2bf(a.z), f2bf(a.w));
    ushort4 o1 = make_ushort4(f2bf(c.x), f2bf(c.y), f2bf(c.z), f2bf(c.w));
    *(ushort4*)(Xb + base) = o0;
    *(ushort4*)(Xb + base + 4) = o1;
  } else if (bid < 7360) {
    int wb = bid - 2560;          // 3 * 1600 tiles of 32x32
    int mat = wb / 1600;
    int t = wb % 1600;
    int tn = t % 40, tk = t / 40;
    const float* W = (mat == 0) ? Wq : ((mat == 1) ? Wk : Wv);
    int k0 = tk * 32, n0 = tn * 32;
    int tc = tid & 31, tr = tid >> 5;
#pragma unroll
    for (int i = 0; i < 4; i++) {
      int kl = tr + i * 8;
      tile[kl][tc] = f2bf(W[(size_t)(k0 + kl) * DD + n0 + tc]);
    }
    __syncthreads();
    unsigned short* out = WT + (size_t)mat * DD * DD;
#pragma unroll
    for (int i = 0; i < 4; i++) {
      int nl = tr + i * 8;
      out[(size_t)(n0 + nl) * DD + k0 + tc] = tile[tc][nl];
    }
  } else {
    // rotary table: cs[sp][j] = (cos, sin)(sp * 10000^(-j/32)), 2048 x 32
    int idx = (bid - 7360) * 256 + tid;     // 256 blocks -> 65536 entries
    int sp = idx >> 5, j = idx & 31;
    float invf = exp2f(-(float)j * 0.41524101186092034f);
    float ang = (float)sp * invf;
    cs[idx] = make_float2(cosf(ang), sinf(ang));
  }
}

// ---- QKV GEMM (m97 structure) + fused bias + rotary (table) epilogue ----
// Q additionally scaled by HD^-0.5 * log2(e) so attention can use exp2 directly.
__global__ __launch_bounds__(256) void qkv_gemm_kernel(
    const unsigned short* __restrict__ Xb, const unsigned short* __restrict__ WT,
    const float* __restrict__ bq, const float* __restrict__ bk, const float* __restrict__ bv,
    const float2* __restrict__ cs,
    unsigned short* __restrict__ Qr, unsigned short* __restrict__ Kr,
    unsigned short* __restrict__ VT) {
  __shared__ __align__(16) unsigned short As[128 * 32];
  __shared__ __align__(16) unsigned short Bs[128 * 32];
  int bx = blockIdx.x;            // 3 * 32 * 10
  int mat = bx / 320;
  int r0 = bx % 320;
  int tm = r0 / 10, tn = r0 % 10;
  int m0 = tm * 128, n0 = tn * 128;
  int tid = threadIdx.x;
  int lane = tid & 63, wave = tid >> 6;
  int c15 = lane & 15, quad = lane >> 4;
  int wm = wave >> 1, wn = wave & 1;
  const unsigned short* Wm = WT + (size_t)mat * DD * DD;

  int rowA = tid >> 2;
  int c8 = (tid & 3) * 8;
  const unsigned short* gA0 = Xb + (size_t)(m0 + rowA) * DD + c8;
  const unsigned short* gA1 = gA0 + (size_t)64 * DD;
  const unsigned short* gB0 = Wm + (size_t)(n0 + rowA) * DD + c8;
  const unsigned short* gB1 = gB0 + (size_t)64 * DD;
  unsigned short* ldsA0 = As + wave * 512;          // rows 0..63
  unsigned short* ldsA1 = As + 2048 + wave * 512;   // rows 64..127
  unsigned short* ldsB0 = Bs + wave * 512;
  unsigned short* ldsB1 = Bs + 2048 + wave * 512;

  f32x4 acc[4][4] = {};

  for (int kk = 0; kk < DD; kk += 32) {
    __syncthreads();
    GLL16(gA0 + kk, ldsA0);
    GLL16(gA1 + kk, ldsA1);
    GLL16(gB0 + kk, ldsB0);
    GLL16(gB1 + kk, ldsB1);
    __syncthreads();
    bf16x8 af[4];
#pragma unroll
    for (int mi = 0; mi < 4; mi++)
      af[mi] = *(const bf16x8*)(As + (wm * 64 + mi * 16 + c15) * 32 + quad * 8);
#pragma unroll
    for (int ni = 0; ni < 4; ni++) {
      bf16x8 bfr = *(const bf16x8*)(Bs + (wn * 64 + ni * 16 + c15) * 32 + quad * 8);
#pragma unroll
      for (int mi = 0; mi < 4; mi++)
        acc[mi][ni] = __builtin_amdgcn_mfma_f32_16x16x32_bf16(af[mi], bfr, acc[mi][ni], 0, 0, 0);
    }
  }

  int growb = m0 + wm * 64;
  int gcolb = n0 + wn * 64;
  if (mat == 2) {
    // V: write transposed VT[(b*H+h)*64+d][s]
#pragma unroll
    for (int mi = 0; mi < 4; mi++) {
      int row0 = growb + mi * 16 + quad * 4;
      int bb_ = row0 >> 11, sp = row0 & 2047;
#pragma unroll
      for (int ni = 0; ni < 4; ni++) {
        int gcol = gcolb + ni * 16 + c15;
        float bias = bv[gcol];
        int hh = gcol >> 6, dd = gcol & 63;
        f32x4 v = acc[mi][ni];
        ushort4 o = make_ushort4(f2bf(v[0] + bias), f2bf(v[1] + bias),
                                 f2bf(v[2] + bias), f2bf(v[3] + bias));
        *(ushort4*)(VT + ((size_t)((bb_ * HH + hh) * 64 + dd)) * SS + sp) = o;
      }
    }
  } else {
    // Q / K: bias + rotary via cs table; each wave's 64 cols = exactly one head,
    // rotary pair (d, d+32) = acc frags (ni, ni+2), same lane.
    unsigned short* Out = (mat == 0) ? Qr : Kr;
    const float* bias = (mat == 0) ? bq : bk;
    float qs = (mat == 0) ? 0.18033688011112042f : 1.0f;  // 0.125*log2(e) for Q
#pragma unroll
    for (int mi = 0; mi < 4; mi++) {
      int row0 = growb + mi * 16 + quad * 4;
#pragma unroll
      for (int ni = 0; ni < 2; ni++) {
        int gcol_lo = gcolb + ni * 16 + c15;      // d in [0,32) within head
        int gcol_hi = gcol_lo + 32;
        float blo = bias[gcol_lo], bhi = bias[gcol_hi];
        int d = ni * 16 + c15;
        f32x4 lo = acc[mi][ni], hi = acc[mi][ni + 2];
#pragma unroll
        for (int r = 0; r < 4; r++) {
          int grow = row0 + r;
          float2 cv = cs[(size_t)(grow & 2047) * 32 + d];
          float xl = (lo[r] + blo) * qs, xh = (hi[r] + bhi) * qs;
          Out[(size_t)grow * DD + gcol_lo] = f2bf(xl * cv.x - xh * cv.y);
          Out[(size_t)grow * DD + gcol_hi] = f2bf(xh * cv.x + xl * cv.y);
        }
      }
    }
  }
}

// ---- flash attention v6: key-split waves + 2-stage register pipeline ----
// The t-loop has NO barriers, so K/V fragments are double-buffered in VGPRs:
// tile t+1's 8 loads issue before tile t's compute (full compute phase covers
// the L2 latency; compiler can use vmcnt(8)). P strips are produced/consumed
// per-mi (write mi, consume mi-1) so LDS drain overlaps PV-MFMA.
// Budget: ~168 arch + 80 acc = ~248 <= 256 (waves_per_eu min=2). Spill
// tripwire: WRITE_SIZE > ~25 MB.
__device__ __forceinline__ void attn_load_frags(
    bf16x8 (&kf)[2][2], bf16x8 (&vf)[4],
    const unsigned short* Kt, const unsigned short* Vt, int c15, int quad) {
#pragma unroll
  for (int ni = 0; ni < 2; ni++)
#pragma unroll
    for (int kc = 0; kc < 2; kc++)
      kf[ni][kc] = *(const bf16x8*)(Kt + (size_t)(ni * 16 + c15) * DD + kc * 32 + quad * 8);
#pragma unroll
  for (int nio = 0; nio < 4; nio++)
    vf[nio] = *(const bf16x8*)(Vt + (size_t)(nio * 16 + c15) * SS + quad * 8);
}

__device__ __forceinline__ void attn_tile(
    const bf16x8 (&qf)[4][2], const bf16x8 (&kf)[2][2], const bf16x8 (&vf)[4],
    const bf16x8& ones, f32x4 (&of)[4][4], f32x4 (&ol)[4],
    unsigned short* Pw, int c15, int quad) {
  // S = Q K^T  (64q x 32k per wave)
  f32x4 sc[4][2] = {};
#pragma unroll
  for (int ni = 0; ni < 2; ni++)
#pragma unroll
    for (int kc = 0; kc < 2; kc++)
#pragma unroll
      for (int mi = 0; mi < 4; mi++)
        sc[mi][ni] = __builtin_amdgcn_mfma_f32_16x16x32_bf16(qf[mi][kc], kf[ni][kc], sc[mi][ni], 0, 0, 0);

  int pos_r = (quad + 2 * ((c15 >> 2) & 3) + (c15 & 3)) & 7;   // read-side swizzle

#define PROD(mi)                                                              \
  {                                                                           \
    _Pragma("unroll")                                                         \
    for (int ni = 0; ni < 2; ni++) {                                          \
      int kc8 = ni * 2 + (c15 >> 3);                                          \
      _Pragma("unroll")                                                       \
      for (int r = 0; r < 4; r++) {                                           \
        unsigned u = f2u(__builtin_amdgcn_exp2f(sc[mi][ni][r]));              \
        int q = (mi) * 16 + quad * 4 + r;                                     \
        int pos = (kc8 + 2 * quad + r) & 7;                                   \
        Pw[q * 64 + pos * 8 + (c15 & 7)] = (unsigned short)(u >> 16);         \
      }                                                                       \
    }                                                                         \
  }
#define CONS(mi)                                                              \
  {                                                                           \
    bf16x8 pf = *(const bf16x8*)(Pw + ((mi) * 16 + c15) * 64 + pos_r * 8);    \
    _Pragma("unroll")                                                         \
    for (int nio = 0; nio < 4; nio++)                                         \
      of[mi][nio] = __builtin_amdgcn_mfma_f32_16x16x32_bf16(pf, vf[nio],      \
                                                            of[mi][nio], 0, 0, 0); \
    ol[mi] = __builtin_amdgcn_mfma_f32_16x16x32_bf16(pf, ones, ol[mi], 0, 0, 0); \
  }

  PROD(0);
  PROD(1); CONS(0);
  PROD(2); CONS(1);
  PROD(3); CONS(2);
  CONS(3);
#undef PROD
#undef CONS
}

__global__ __launch_bounds__(256)
__attribute__((amdgpu_waves_per_eu(2, 4)))
void attn_kernel(
    const unsigned short* __restrict__ Qr, const unsigned short* __restrict__ Kr,
    const unsigned short* __restrict__ VT, float* __restrict__ out) {
  __shared__ __align__(16) unsigned short Pall[4 * 64 * 64];  // 32 KB: per-wave P strips
  __shared__ float Lbuf[64];
  int bx = blockIdx.x;             // bx = qt*40 + bh; head pinned to one XCD (40%8==0)
  int bh = bx % 40, qt = bx / 40;
  int b = bh / HH, h = bh % HH;
  int tid = threadIdx.x;
  int lane = tid & 63, w = tid >> 6;
  int c15 = lane & 15, quad = lane >> 4;
  int q0 = qt * 64;

  // Q frags direct from global (A-layout: lane m=c15, k=quad*8), kept in regs
  const unsigned short* Qbase = Qr + (size_t)(b * SS + q0) * DD + h * 64;
  bf16x8 qf[4][2];
#pragma unroll
  for (int mi = 0; mi < 4; mi++)
#pragma unroll
    for (int kc = 0; kc < 2; kc++)
      qf[mi][kc] = *(const bf16x8*)(Qbase + (size_t)(mi * 16 + c15) * DD + kc * 32 + quad * 8);

  const unsigned short* Kbase = Kr + (size_t)(b * SS + w * 32) * DD + h * 64;
  const unsigned short* Vbase = VT + (size_t)(bh * 64) * SS + w * 32;
  unsigned short* Pw = Pall + w * 4096;   // 64 rows x 64 shorts

  bf16x8 ones;
#pragma unroll
  for (int i = 0; i < 8; i++) ones[i] = (__bf16)1.0f;

  f32x4 of[4][4] = {};       // [mi][nio]
  f32x4 ol[4] = {};          // l via P*ones

  bf16x8 kfb[2][2][2], vfb[2][4];   // double-buffered K/V fragments
  attn_load_frags(kfb[0], vfb[0], Kbase, Vbase, c15, quad);

  for (int t = 0; t < 16; t += 2) {
    // issue t+1 loads into buf1 before computing buf0
    attn_load_frags(kfb[1], vfb[1],
                    Kbase + (size_t)((t + 1) * 128) * DD, Vbase + (t + 1) * 128,
                    c15, quad);
    attn_tile(qf, kfb[0], vfb[0], ones, of, ol, Pw, c15, quad);
    if (t + 2 < 16)
      attn_load_frags(kfb[0], vfb[0],
                      Kbase + (size_t)((t + 2) * 128) * DD, Vbase + (t + 2) * 128,
                      c15, quad);
    attn_tile(qf, kfb[1], vfb[1], ones, of, ol, Pw, c15, quad);
  }

  // all waves done with their P strips -> safe to overlay Obuf on Pall
  __syncthreads();
  float* Obuf = (float*)Pall;      // 64 x 65 floats = 16.6 KB of the 32 KB strip area

  // cross-wave reduction of O and l (serialized passes)
  for (int pass = 0; pass < 4; pass++) {
    if (w == pass) {
#pragma unroll
      for (int mi = 0; mi < 4; mi++)
#pragma unroll
        for (int nio = 0; nio < 4; nio++)
#pragma unroll
          for (int r = 0; r < 4; r++) {
            int q = mi * 16 + quad * 4 + r;
            int d = nio * 16 + c15;
            if (pass == 0) Obuf[q * 65 + d] = of[mi][nio][r];
            else           Obuf[q * 65 + d] += of[mi][nio][r];
          }
      if (c15 == 0) {
#pragma unroll
        for (int mi = 0; mi < 4; mi++)
#pragma unroll
          for (int r = 0; r < 4; r++) {
            int q = mi * 16 + quad * 4 + r;
            if (pass == 0) Lbuf[q] = ol[mi][r];
            else           Lbuf[q] += ol[mi][r];
          }
      }
    }
    __syncthreads();
  }

  // epilogue: each wave writes 16 q-rows; lane covers 16 consecutive d
  {
    int row = w * 16 + (lane >> 2);
    int col0 = (lane & 3) * 16;
    float invl = 1.0f / Lbuf[row];
    float* op = out + (size_t)(b * SS + q0 + row) * DD + h * 64 + col0;
    const float* ob = Obuf + row * 65 + col0;
#pragma unroll
    for (int j = 0; j < 4; j++) {
      float4 v = make_float4(ob[j * 4 + 0] * invl, ob[j * 4 + 1] * invl,
                             ob[j * 4 + 2] * invl, ob[j * 4 + 3] * invl);
      *(float4*)(op + j * 4) = v;
    }
  }
}

extern "C" void kernel_launch(void* const* d_in, const int* in_sizes, int n_in,
                              void* d_out, int out_size, void* d_ws, size_t ws_size,
                              hipStream_t stream) {
  (void)in_sizes; (void)n_in; (void)out_size; (void)ws_size;
  const float* X  = (const float*)d_in[0];
  const float* Wq = (const float*)d_in[1];
  const float* bq = (const float*)d_in[2];
  const float* Wk = (const float*)d_in[3];
  const float* bk = (const float*)d_in[4];
  const float* Wv = (const float*)d_in[5];
  const float* bv = (const float*)d_in[6];
  char* ws = (char*)d_ws;
  unsigned short* Xb  = (unsigned short*)(ws);                 // 4096x1280 bf16
  unsigned short* WT  = (unsigned short*)(ws + 10485760);      // 3x1280x1280 bf16 (transposed)
  unsigned short* Qr  = (unsigned short*)(ws + 20316160);      // 4096x1280 bf16 (rotary'd, scaled)
  unsigned short* Kr  = (unsigned short*)(ws + 30801920);      // 4096x1280 bf16 (rotary'd)
  unsigned short* VTt = (unsigned short*)(ws + 41287680);      // [40][64][2048] bf16
  float2* cstab       = (float2*)(ws + 51773440);              // 2048x32 float2
  hipLaunchKernelGGL(prep_kernel, dim3(7616), dim3(256), 0, stream, X, Wq, Wk, Wv, Xb, WT, cstab);
  hipLaunchKernelGGL(qkv_gemm_kernel, dim3(960), dim3(256), 0, stream, Xb, WT, bq, bk, bv, cstab, Qr, Kr, VTt);
  hipLaunchKernelGGL(attn_kernel, dim3(1280), dim3(256), 0, stream, Qr, Kr, VTt, (float*)d_out);
}